// Round 5
// baseline (459.840 us; speedup 1.0000x reference)
//
#include <hip/hip_runtime.h>
#include <hip/hip_bf16.h>

typedef unsigned short u16;
typedef unsigned int   u32;
typedef __attribute__((ext_vector_type(8))) short short8;
typedef __attribute__((ext_vector_type(4))) float f32x4;

#define NN 320
#define NP (NN*NN)
#define DD 128
#define NH 4
#define DHH 32
#define QSCALE 0.17677669529663687f
#define LOG2E  1.4426950408889634f

#define MFMA16(A,B,C) __builtin_amdgcn_mfma_f32_16x16x32_bf16(A,B,C,0,0,0)

__device__ __forceinline__ float b2f(u16 u){
    union { u32 i; float f; } v; v.i = ((u32)u) << 16; return v.f;
}
__device__ __forceinline__ u16 f2b(float f){
    union { float f; u32 i; } v; v.f = f;
    u32 x = v.i;
    u32 r = x + 0x7fffu + ((x >> 16) & 1u);
    return (u16)(r >> 16);
}
__device__ __forceinline__ u32 cvtpk(float lo, float hi){
    u32 r; asm("v_cvt_pk_bf16_f32 %0, %1, %2" : "=v"(r) : "v"(lo), "v"(hi)); return r;
}
__device__ __forceinline__ float fexp2(float x){
    float r; asm("v_exp_f32 %0, %1" : "=v"(r) : "v"(x)); return r;
}
__device__ __forceinline__ float frcp(float x){
    float r; asm("v_rcp_f32 %0, %1" : "=v"(r) : "v"(x)); return r;
}

// ---------------- LayerNorm + edge-bias kernel ----------------
// One wave per position p. xn = bf16 LN output. bias[h][i][j] = (x[i][j].wb[h]) * LOG2E
__global__ __launch_bounds__(256) void k_ln_bias(
    const float* __restrict__ xin, const float* __restrict__ ng, const float* __restrict__ nb,
    const float* __restrict__ wb, u16* __restrict__ xn, float* __restrict__ bias)
{
    const int w = threadIdx.x >> 6, lane = threadIdx.x & 63;
    const int p = blockIdx.x * 4 + w;
    const int d0 = lane * 2;
    const float2 xp = *(const float2*)(xin + (size_t)p*DD + d0);
    const float x0 = xp.x, x1 = xp.y;
    float s = x0 + x1;
    #pragma unroll
    for (int m = 1; m < 64; m <<= 1) s += __shfl_xor(s, m);
    const float mu = s * (1.f/128.f);
    const float dx0 = x0 - mu, dx1 = x1 - mu;
    float vv = dx0*dx0 + dx1*dx1;
    #pragma unroll
    for (int m = 1; m < 64; m <<= 1) vv += __shfl_xor(vv, m);
    const float rstd = rsqrtf(vv * (1.f/128.f) + 1e-5f);
    const float2 gp = *(const float2*)(ng + d0);
    const float2 bp = *(const float2*)(nb + d0);
    const float y0 = dx0*rstd*gp.x + bp.x;
    const float y1 = dx1*rstd*gp.y + bp.y;
    const u32 ow = (u32)f2b(y0) | ((u32)f2b(y1) << 16);
    *(u32*)(xn + (size_t)p*DD + d0) = ow;
    #pragma unroll
    for (int h = 0; h < NH; ++h){
        const float2 wp = *(const float2*)(wb + h*DD + d0);
        float bb = x0*wp.x + x1*wp.y;
        #pragma unroll
        for (int m = 1; m < 64; m <<= 1) bb += __shfl_xor(bb, m);
        if (lane == 0) bias[(size_t)h*NP + p] = bb * LOG2E;
    }
}

// ---------------- Fused QKVG GEMM: stage A once, 4 weight tiles ----------------
// p=0: Q (*QSCALE*LOG2E)  p=1: K  p=2: V  p=3: G (sigmoid(+bg))
__global__ __launch_bounds__(256) void k_qkvg(
    const u16* __restrict__ Amat, const float* __restrict__ wq, const float* __restrict__ wkv,
    const float* __restrict__ wg, const float* __restrict__ bg,
    u16* __restrict__ Pq, u16* __restrict__ Pk, u16* __restrict__ Pv, u16* __restrict__ Pg)
{
    __shared__ u16 As[128*128];   // [row][k], 16B-slot swizzle: slot ^= row&7
    __shared__ u16 Ws[128*128];
    const int tid = threadIdx.x;
    const int pbase = blockIdx.x * 128;

    #pragma unroll
    for (int c = 0; c < 8; ++c){
        const int flat = tid + c*256;
        const int row = flat >> 4, s = flat & 15;
        const uint4 a4 = *(const uint4*)(Amat + (size_t)(pbase+row)*DD + s*8);
        *(uint4*)&As[row*128 + ((s ^ (row & 7)) << 3)] = a4;
    }

    const int w = tid >> 6, l = tid & 63;
    const int li = l & 15, g = l >> 4;
    const int wr = w >> 1, wc = w & 1;

    for (int p = 0; p < 4; ++p){
        const float* W = (p == 0) ? wq : (p == 1) ? wkv : (p == 2) ? (wkv + DD*DD) : wg;
        // stage W tile (f32 -> bf16)
        #pragma unroll
        for (int c = 0; c < 8; ++c){
            const int flat = tid + c*256;
            const int row = flat >> 4, s = flat & 15;
            const float4 wa  = *(const float4*)(W + (size_t)row*DD + s*8);
            const float4 wbv = *(const float4*)(W + (size_t)row*DD + s*8 + 4);
            union { uint4 q; u16 us[8]; } ww;
            ww.us[0]=f2b(wa.x);  ww.us[1]=f2b(wa.y);  ww.us[2]=f2b(wa.z);  ww.us[3]=f2b(wa.w);
            ww.us[4]=f2b(wbv.x); ww.us[5]=f2b(wbv.y); ww.us[6]=f2b(wbv.z); ww.us[7]=f2b(wbv.w);
            *(uint4*)&Ws[row*128 + ((s ^ (row & 7)) << 3)] = ww.q;
        }
        __syncthreads();

        f32x4 acc[4][4] = {};
        #pragma unroll
        for (int ks = 0; ks < 4; ++ks){
            const int slot = ks*4 + g;
            short8 af[4];
            #pragma unroll
            for (int mt = 0; mt < 4; ++mt){
                const int row = wr*64 + mt*16 + li;
                af[mt] = *(const short8*)&As[row*128 + ((slot ^ (row & 7)) << 3)];
            }
            #pragma unroll
            for (int nt = 0; nt < 4; ++nt){
                const int e = wc*64 + nt*16 + li;
                const short8 bfv = *(const short8*)&Ws[e*128 + ((slot ^ (e & 7)) << 3)];
                #pragma unroll
                for (int mt = 0; mt < 4; ++mt)
                    acc[mt][nt] = MFMA16(af[mt], bfv, acc[mt][nt]);
            }
        }

        u16* Op = (p == 0) ? Pq : (p == 1) ? Pk : (p == 2) ? Pv : Pg;
        #pragma unroll
        for (int mt = 0; mt < 4; ++mt){
            #pragma unroll
            for (int nt = 0; nt < 4; ++nt){
                const int e = wc*64 + nt*16 + li;
                #pragma unroll
                for (int q = 0; q < 4; ++q){
                    const size_t pos = (size_t)pbase + wr*64 + mt*16 + g*4 + q;
                    float v = acc[mt][nt][q];
                    if (p == 0) v *= (QSCALE * LOG2E);
                    else if (p == 3) v = frcp(1.f + fexp2(-LOG2E*(v + bg[e])));
                    Op[pos*DD + e] = f2b(v);
                }
            }
        }
        __syncthreads();
    }
}

// ---------------- Output-projection GEMM (+bo +residual -> f32) ----------------
__global__ __launch_bounds__(256) void k_oproj(
    const u16* __restrict__ Amat, const float* __restrict__ Wmat, float* __restrict__ Outp,
    const float* __restrict__ bov, const float* __restrict__ xres)
{
    __shared__ u16 As[128*128];
    __shared__ u16 Ws[128*128];
    const int tid = threadIdx.x;
    const int pbase = blockIdx.x * 128;

    #pragma unroll
    for (int c = 0; c < 8; ++c){
        const int flat = tid + c*256;
        const int row = flat >> 4, s = flat & 15;
        const uint4 a4 = *(const uint4*)(Amat + (size_t)(pbase+row)*DD + s*8);
        *(uint4*)&As[row*128 + ((s ^ (row & 7)) << 3)] = a4;
        const float4 wa  = *(const float4*)(Wmat + (size_t)row*DD + s*8);
        const float4 wbv = *(const float4*)(Wmat + (size_t)row*DD + s*8 + 4);
        union { uint4 q; u16 us[8]; } ww;
        ww.us[0]=f2b(wa.x);  ww.us[1]=f2b(wa.y);  ww.us[2]=f2b(wa.z);  ww.us[3]=f2b(wa.w);
        ww.us[4]=f2b(wbv.x); ww.us[5]=f2b(wbv.y); ww.us[6]=f2b(wbv.z); ww.us[7]=f2b(wbv.w);
        *(uint4*)&Ws[row*128 + ((s ^ (row & 7)) << 3)] = ww.q;
    }
    __syncthreads();

    const int w = tid >> 6, l = tid & 63;
    const int li = l & 15, g = l >> 4;
    const int wr = w >> 1, wc = w & 1;
    f32x4 acc[4][4] = {};

    #pragma unroll
    for (int ks = 0; ks < 4; ++ks){
        const int slot = ks*4 + g;
        short8 af[4];
        #pragma unroll
        for (int mt = 0; mt < 4; ++mt){
            const int row = wr*64 + mt*16 + li;
            af[mt] = *(const short8*)&As[row*128 + ((slot ^ (row & 7)) << 3)];
        }
        #pragma unroll
        for (int nt = 0; nt < 4; ++nt){
            const int e = wc*64 + nt*16 + li;
            const short8 bfv = *(const short8*)&Ws[e*128 + ((slot ^ (e & 7)) << 3)];
            #pragma unroll
            for (int mt = 0; mt < 4; ++mt)
                acc[mt][nt] = MFMA16(af[mt], bfv, acc[mt][nt]);
        }
    }

    #pragma unroll
    for (int mt = 0; mt < 4; ++mt){
        #pragma unroll
        for (int nt = 0; nt < 4; ++nt){
            const int e = wc*64 + nt*16 + li;
            #pragma unroll
            for (int q = 0; q < 4; ++q){
                const size_t pos = (size_t)pbase + wr*64 + mt*16 + g*4 + q;
                Outp[pos*DD + e] = acc[mt][nt][q] + bov[e] + xres[pos*DD + e];
            }
        }
    }
}

// ---------------- MFMA attention: one block per (h, r), 4 waves x 5 Q-tiles ----------------
// Swapped QK^T with bias as C-operand; row-max-subtracted exp2 softmax;
// V staged j-permuted so PV A-frags are lane-local (zero shuffles);
// denominators via ones-MFMA (lands in epilogue layout directly).
template<int ROWPASS>
__global__ __launch_bounds__(256) void k_attn_mfma(
    const u16* __restrict__ Pq, const u16* __restrict__ Pk, const u16* __restrict__ Pv,
    const u16* __restrict__ Pg, const float* __restrict__ bias, u16* __restrict__ Aout)
{
    __shared__ u16 ks[320*32];   // [j][e], 16B-slot swizzle: slot ^= (j>>1)&3  (2-way = free)
    __shared__ u16 vt[32*320];   // [e][j'], j' = PV-permuted j, slot swizzle: slot ^= e&7
    const int h = blockIdx.x, r = blockIdx.y;
    const int tid = threadIdx.x;

    #pragma unroll
    for (int c = 0; c < 5; ++c){
        const int flat = tid + c*256;      // 0..1279
        const int j = flat >> 2, s = flat & 3;
        const size_t pos = ROWPASS ? ((size_t)r*NN + j) : ((size_t)j*NN + r);
        const uint4 k4 = *(const uint4*)(Pk + pos*DD + h*DHH + s*8);
        *(uint4*)&ks[j*32 + ((s ^ ((j >> 1) & 3)) << 3)] = k4;
        const uint4 v4 = *(const uint4*)(Pv + pos*DD + h*DHH + s*8);
        union { uint4 q; u16 us[8]; } vu; vu.q = v4;
        // PV permutation: j' places this j at A-frag k-slot (jp = j3*16 + j2*8 + j4*4 + j1*2 + j0)
        const int jp = (j & ~31) + ((j >> 2) & 3)*8 + ((j >> 4) & 1)*4 + (j & 3);
        #pragma unroll
        for (int u = 0; u < 8; ++u){
            const int e = s*8 + u;
            vt[e*320 + (((jp >> 3) ^ (e & 7)) << 3) + (jp & 7)] = vu.us[u];
        }
    }
    __syncthreads();

    const int w = tid >> 6, l = tid & 63;
    const int li = l & 15, g = l >> 4;
    const short8 ones = {0x3F80,0x3F80,0x3F80,0x3F80,0x3F80,0x3F80,0x3F80,0x3F80};

    for (int t = 0; t < 5; ++t){
        const int i0 = (w + t*4) * 16;
        const int iq = i0 + li;
        const size_t qpos = ROWPASS ? ((size_t)r*NN + iq) : ((size_t)iq*NN + r);
        const short8 qf = *(const short8*)(Pq + qpos*DD + h*DHH + g*8);

        // bias -> C operands (f32x4, q-consecutive j)
        f32x4 st[20];
        const float* bp = bias + (size_t)h*NP + (size_t)iq*NN + g*4;
        #pragma unroll
        for (int jt = 0; jt < 20; ++jt)
            st[jt] = *(const f32x4*)(bp + jt*16);

        // QK^T accumulate on top of bias
        #pragma unroll
        for (int jt = 0; jt < 20; ++jt){
            const int jr = jt*16 + li;
            const short8 kf = *(const short8*)&ks[jr*32 + ((g ^ ((jr >> 1) & 3)) << 3)];
            st[jt] = MFMA16(kf, qf, st[jt]);
        }

        // row max (lane-local 80 values, then reduce over the 4 g-lanes sharing li)
        float mx = -1e30f;
        #pragma unroll
        for (int jt = 0; jt < 20; ++jt)
            mx = fmaxf(mx, fmaxf(fmaxf(st[jt][0], st[jt][1]), fmaxf(st[jt][2], st[jt][3])));
        mx = fmaxf(mx, __shfl_xor(mx, 16));
        mx = fmaxf(mx, __shfl_xor(mx, 32));

        // exp2(score - max); scores pre-scaled by log2e
        #pragma unroll
        for (int jt = 0; jt < 20; ++jt){
            #pragma unroll
            for (int q = 0; q < 4; ++q)
                st[jt][q] = fexp2(st[jt][q] - mx);
        }

        // PV + denominator, zero shuffles
        f32x4 o0 = {0.f,0.f,0.f,0.f}, o1 = {0.f,0.f,0.f,0.f}, osum = {0.f,0.f,0.f,0.f};
        #pragma unroll
        for (int kt = 0; kt < 10; ++kt){
            union { u32 u[4]; short8 s8; } pu;
            pu.u[0] = cvtpk(st[2*kt][0],   st[2*kt][1]);
            pu.u[1] = cvtpk(st[2*kt][2],   st[2*kt][3]);
            pu.u[2] = cvtpk(st[2*kt+1][0], st[2*kt+1][1]);
            pu.u[3] = cvtpk(st[2*kt+1][2], st[2*kt+1][3]);
            const int slot = ((kt*4 + g) ^ (li & 7)) << 3;
            const short8 v0 = *(const short8*)&vt[li*320 + slot];
            const short8 v1 = *(const short8*)&vt[(16+li)*320 + slot];
            o0   = MFMA16(pu.s8, v0,   o0);
            o1   = MFMA16(pu.s8, v1,   o1);
            osum = MFMA16(pu.s8, ones, osum);
        }

        // epilogue: rows i = i0+4g+q (osum matches this layout; no shuffles)
        float invq[4];
        #pragma unroll
        for (int q = 0; q < 4; ++q) invq[q] = frcp(osum[q]);
        #pragma unroll
        for (int et = 0; et < 2; ++et){
            const f32x4 oo = et ? o1 : o0;
            #pragma unroll
            for (int q = 0; q < 4; ++q){
                const int i = i0 + g*4 + q;
                const size_t pos = ROWPASS ? ((size_t)r*NN + i) : ((size_t)i*NN + r);
                const size_t off = pos*DD + h*DHH + et*16 + li;
                Aout[off] = f2b(oo[q] * invq[q] * b2f(Pg[off]));
            }
        }
    }
}

// ---------------- host-side launch ----------------
extern "C" void kernel_launch(void* const* d_in, const int* in_sizes, int n_in,
                              void* d_out, int out_size, void* d_ws, size_t ws_size,
                              hipStream_t stream)
{
    const float* x = (const float*)d_in[0];
    float* out = (float*)d_out;
    char* ws = (char*)d_ws;

    u16*   xn   = (u16*)ws;                                   // NP*DD bf16 (aliased as attn out)
    float* bias = (float*)(ws + (size_t)NP*DD*2);             // NH*NP f32, [h][i][j], *LOG2E
    u16*   Pq   = (u16*)(ws + (size_t)NP*DD*2 + (size_t)NH*NP*4);
    u16*   Pk   = Pq + (size_t)NP*DD;
    u16*   Pv   = Pk + (size_t)NP*DD;
    u16*   Pg   = Pv + (size_t)NP*DD;
    u16*   Aatt = xn;   // xn is dead after the projection GEMM

    for (int pass = 0; pass < 2; ++pass){
        void* const* W = d_in + 1 + pass*9;
        const float* ng = (const float*)W[0];
        const float* nb = (const float*)W[1];
        const float* wb = (const float*)W[2];
        const float* wq = (const float*)W[3];
        const float* wkv= (const float*)W[4];
        const float* wg = (const float*)W[5];
        const float* bg = (const float*)W[6];
        const float* wo = (const float*)W[7];
        const float* bo = (const float*)W[8];
        const float* xin = (pass == 0) ? x : out;

        k_ln_bias<<<NP/4, 256, 0, stream>>>(xin, ng, nb, wb, xn, bias);
        k_qkvg<<<NP/128, 256, 0, stream>>>(xn, wq, wkv, wg, bg, Pq, Pk, Pv, Pg);
        if (pass == 0) k_attn_mfma<1><<<dim3(NH, NN), 256, 0, stream>>>(Pq, Pk, Pv, Pg, bias, Aatt);
        else           k_attn_mfma<0><<<dim3(NH, NN), 256, 0, stream>>>(Pq, Pk, Pv, Pg, bias, Aatt);
        k_oproj<<<NP/128, 256, 0, stream>>>(Aatt, wo, out, bo, xin);
    }
}